// Round 8
// baseline (342.297 us; speedup 1.0000x reference)
//
#include <hip/hip_runtime.h>

// Problem constants
#define B_SZ 512
#define C_CH 256
#define L_SEQ 256
#define H_DIM 512
#define T_STEP 16
#define W_WIN 8
#define NSLAB 24   // max distinct l values = T+W-1 = 23, round up
#define NCE_SHIFT 40.0f

typedef __attribute__((ext_vector_type(8))) short short8;
typedef __attribute__((ext_vector_type(4))) float f32x4;

#define GLOBAL_U32 const __attribute__((address_space(1))) unsigned int*
#define LDS_U32 __attribute__((address_space(3))) unsigned int*
// async 16B/lane global->LDS; LDS dest = wave-uniform base + lane*16
#define ASYNC_COPY16(g, l) \
  __builtin_amdgcn_global_load_lds((GLOBAL_U32)(const void*)(g), (LDS_U32)(void*)(l), 16, 0, 0)

__device__ inline unsigned short f2bf(float x) {  // RNE f32 -> bf16
  unsigned u = __float_as_uint(x);
  u = (u + 0x7FFFu + ((u >> 16) & 1u)) >> 16;
  return (unsigned short)u;
}

// ---------------- fused prep: casts (c_t, Wk_w, pw1) + encode slabs ----------------
// grid 4672 blocks x 256: [0,2048) cast c_t; [2048,4096) cast Wk; [4096,4160) cast pw1;
// [4160,4672) slabs (one block per b, thread per c).
__global__ __launch_bounds__(256) void prep_all(const float* __restrict__ c_t,
                                                const float* __restrict__ Wk_w,
                                                const float* __restrict__ pw1,
                                                const float* __restrict__ feat,
                                                unsigned short* __restrict__ ct_bf,
                                                unsigned short* __restrict__ wk_bf,
                                                unsigned short* __restrict__ pw1_bf,
                                                unsigned short* __restrict__ F,
                                                const int* __restrict__ tsp) {
  const int blk = blockIdx.x;
  if (blk < 4160) {  // cast region
    const float* s;
    unsigned short* d;
    int base;
    if (blk < 2048) { s = c_t; d = ct_bf; base = blk; }
    else if (blk < 4096) { s = Wk_w; d = wk_bf; base = blk - 2048; }
    else { s = pw1; d = pw1_bf; base = blk - 4096; }
    int i = base * 256 + threadIdx.x;  // float4 index
    float4 v = ((const float4*)s)[i];
    ushort4 o;
    o.x = f2bf(v.x); o.y = f2bf(v.y); o.z = f2bf(v.z); o.w = f2bf(v.w);
    ((ushort4*)d)[i] = o;
    return;
  }
  const int b = blk - 4160;
  const int c = threadIdx.x;
  const int ts = tsp[0];
  const int lmin = min(ts + 1, L_SEQ - W_WIN);
  const float* src = feat + ((size_t)b * C_CH + c) * L_SEQ;
  float v[NSLAB];
#pragma unroll
  for (int lp = 0; lp < NSLAB; lp++) {
    int l = lmin + lp;
    v[lp] = (l < L_SEQ) ? src[l] : 0.f;
  }
#pragma unroll
  for (int lp = 0; lp < NSLAB; lp++)
    F[((size_t)lp * B_SZ + b) * C_CH + c] = f2bf(v[lp]);
}

// ---------------- bf16 MFMA GEMM: D = A[M,K] * Bt[N,K]^T + bias[col] ----------------
// MODE 0: out = bf16 row-major [M][N] (pred, natural layout)    N=4096
// MODE 1: out = f32 row-major [M][128] (h1 pre-BN)              N=128
template <int MODE>
__global__ __launch_bounds__(256) void gemm_bt(const unsigned short* __restrict__ A,
                                               const unsigned short* __restrict__ Bt,
                                               const float* __restrict__ bias,
                                               unsigned short* __restrict__ outb,
                                               float* __restrict__ outf, int K, int Nld) {
  __shared__ __align__(16) unsigned short As[128 * 64];
  __shared__ __align__(16) unsigned short Bs[128 * 64];
  const int tid = threadIdx.x;
  const int wv = tid >> 6, lane = tid & 63, quad = lane >> 4, l15 = lane & 15;
  const int wm = wv >> 1, wn = wv & 1;
  const int M0 = blockIdx.x * 128, N0 = blockIdx.y * 128;

  f32x4 acc[4][4];
#pragma unroll
  for (int i = 0; i < 4; i++)
#pragma unroll
    for (int j = 0; j < 4; j++) acc[i][j] = (f32x4){0.f, 0.f, 0.f, 0.f};

  for (int k0 = 0; k0 < K; k0 += 64) {
#pragma unroll
    for (int i = 0; i < 4; i++) {
      int chunk = (i * 4 + wv) * 64 + lane;      // 1024 chunks of 16B = [128][64] bf16 tile
      int row = chunk >> 3, off = chunk & 7;     // 8 chunks per 128B row
      const unsigned short* ga = A + (size_t)(M0 + row) * K + k0 + off * 8;
      const unsigned short* gb = Bt + (size_t)(N0 + row) * K + k0 + off * 8;
      ASYNC_COPY16(ga, &As[(size_t)(i * 4 + wv) * 512]);
      ASYNC_COPY16(gb, &Bs[(size_t)(i * 4 + wv) * 512]);
    }
    __syncthreads();  // drains vmcnt
#pragma unroll
    for (int kk = 0; kk < 64; kk += 32) {
      short8 af[4], bfr[4];
#pragma unroll
      for (int i = 0; i < 4; i++)
        af[i] = *(const short8*)&As[(wm * 64 + i * 16 + l15) * 64 + kk + quad * 8];
#pragma unroll
      for (int j = 0; j < 4; j++)
        bfr[j] = *(const short8*)&Bs[(wn * 64 + j * 16 + l15) * 64 + kk + quad * 8];
#pragma unroll
      for (int i = 0; i < 4; i++)
#pragma unroll
        for (int j = 0; j < 4; j++)
          acc[i][j] = __builtin_amdgcn_mfma_f32_16x16x32_bf16(af[i], bfr[j], acc[i][j], 0, 0, 0);
    }
    __syncthreads();
  }

  // epilogue: D mapping col=lane&15, row=quad*4+reg (m89/m91-verified); row-major store
#pragma unroll
  for (int i = 0; i < 4; i++) {
    int rbase = M0 + wm * 64 + i * 16 + quad * 4;
#pragma unroll
    for (int j = 0; j < 4; j++) {
      int cc = N0 + wn * 64 + j * 16 + l15;
      float bv = bias[cc];
#pragma unroll
      for (int r = 0; r < 4; r++) {
        int rr = rbase + r;
        float v = acc[i][j][r] + bv;
        if (MODE == 0) outb[(size_t)rr * Nld + cc] = f2bf(v);
        else outf[(size_t)rr * Nld + cc] = v;
      }
    }
  }
}

// ---------------- scores GEMM tile + exp-sum/diag epilogue ----------------
// grid (128 tw, 4 rowblk, 4 colblk): linear%8 = tw%8 -> all 16 blocks sharing
// pred[tw] on the same XCD. Per tw: scores[b][a] = E[b]·P[a], 512x512, K=256.
// P read DIRECTLY from pred's natural [bw][tc] layout: row a*8+w_, cols t*256+k.
// Epilogue: per-row sum of exp(s-SHIFT), one atomicAdd per row into rowsum[tw][b];
// diagonal blocks write diagv[tw][b].
__global__ __launch_bounds__(256) void scores_gemm(const unsigned short* __restrict__ F,
                                                   const unsigned short* __restrict__ pred,
                                                   const int* __restrict__ tsp,
                                                   float* __restrict__ rowsum,
                                                   float* __restrict__ diagv) {
  __shared__ __align__(16) unsigned short As[128 * 64];
  __shared__ __align__(16) unsigned short Bs[128 * 64];
  const int tid = threadIdx.x;
  const int wv = tid >> 6, lane = tid & 63, quad = lane >> 4, l15 = lane & 15;
  const int wm = wv >> 1, wn = wv & 1;
  const int tw = blockIdx.x, rowblk = blockIdx.y, colblk = blockIdx.z;
  const int t = tw >> 3, w_ = tw & 7;
  const int ts = tsp[0];
  const int lmin = min(ts + 1, L_SEQ - W_WIN);
  const int lp = min(ts + 1 + t, L_SEQ - W_WIN) + w_ - lmin;
  const unsigned short* A = F + (size_t)lp * (B_SZ * C_CH) + (size_t)rowblk * 128 * C_CH;
  // B-tile row j -> pred[(colblk*128+j)*8 + w_][t*256 + k]
  const unsigned short* Bt = pred + ((size_t)(colblk * 128) * 8 + w_) * 4096 + t * 256;

  f32x4 acc[4][4];
#pragma unroll
  for (int i = 0; i < 4; i++)
#pragma unroll
    for (int j = 0; j < 4; j++) acc[i][j] = (f32x4){0.f, 0.f, 0.f, 0.f};

  for (int k0 = 0; k0 < C_CH; k0 += 64) {
#pragma unroll
    for (int i = 0; i < 4; i++) {
      int chunk = (i * 4 + wv) * 64 + lane;
      int row = chunk >> 3, off = chunk & 7;
      ASYNC_COPY16(A + (size_t)row * C_CH + k0 + off * 8, &As[(size_t)(i * 4 + wv) * 512]);
      ASYNC_COPY16(Bt + (size_t)row * 8 * 4096 + k0 + off * 8, &Bs[(size_t)(i * 4 + wv) * 512]);
    }
    __syncthreads();
#pragma unroll
    for (int kk = 0; kk < 64; kk += 32) {
      short8 af[4], bfr[4];
#pragma unroll
      for (int i = 0; i < 4; i++)
        af[i] = *(const short8*)&As[(wm * 64 + i * 16 + l15) * 64 + kk + quad * 8];
#pragma unroll
      for (int j = 0; j < 4; j++)
        bfr[j] = *(const short8*)&Bs[(wn * 64 + j * 16 + l15) * 64 + kk + quad * 8];
#pragma unroll
      for (int i = 0; i < 4; i++)
#pragma unroll
        for (int j = 0; j < 4; j++)
          acc[i][j] = __builtin_amdgcn_mfma_f32_16x16x32_bf16(af[i], bfr[j], acc[i][j], 0, 0, 0);
    }
    __syncthreads();
  }

  // epilogue: per-row (b) partial sum of exp over this block's 128 cols
#pragma unroll
  for (int i = 0; i < 4; i++) {
#pragma unroll
    for (int r = 0; r < 4; r++) {
      float e = 0.f;
#pragma unroll
      for (int j = 0; j < 4; j++) e += __expf(acc[i][j][r] - NCE_SHIFT);
      e += __shfl_xor(e, 1);
      e += __shfl_xor(e, 2);
      e += __shfl_xor(e, 4);
      e += __shfl_xor(e, 8);
      if (l15 == 0) {
        int b = rowblk * 128 + wm * 64 + i * 16 + quad * 4 + r;
        atomicAdd(&rowsum[(size_t)tw * B_SZ + b], e);
      }
    }
  }
  if (rowblk == colblk && wm == wn) {
#pragma unroll
    for (int i = 0; i < 4; i++)
#pragma unroll
      for (int r = 0; r < 4; r++)
        if (l15 == quad * 4 + r) {
          int b = rowblk * 128 + wm * 64 + i * 16 + quad * 4 + r;
          diagv[(size_t)tw * B_SZ + b] = acc[i][i][r];
        }
  }
}

// ---------------- nce reduction over 65536 rows ----------------
__global__ __launch_bounds__(256) void nce_rows(const float* __restrict__ rowsum,
                                                const float* __restrict__ diagv,
                                                float* __restrict__ parts) {
  int gid = blockIdx.x * 256 + threadIdx.x;  // 16384 threads
  float s = 0.f;
  for (int i = gid; i < 65536; i += 16384)
    s += logf(rowsum[i]) + NCE_SHIFT - diagv[i];  // = -logp_diag
  __shared__ float r[256];
  r[threadIdx.x] = s;
  __syncthreads();
  if (threadIdx.x == 0) {
    float t = 0.f;
    for (int k = 0; k < 256; k++) t += r[k];
    parts[blockIdx.x] = t;
  }
}

// ---------------- BN train stats stage 1 (fp32) ----------------
__global__ void bn_stage1(const float* __restrict__ h1, float* __restrict__ p1,
                          float* __restrict__ p2) {
  int c = threadIdx.x;  // 128 threads
  int blk = blockIdx.x; // 32 blocks x 128 rows
  float s1 = 0.f, s2 = 0.f;
  for (int r = blk * 128; r < blk * 128 + 128; r++) {
    float v = h1[(size_t)r * 128 + c];
    s1 += v;
    s2 += v * v;
  }
  p1[blk * 128 + c] = s1;
  p2[blk * 128 + c] = s2;
}

// ---------------- mids: BN stage-2 (scale/shift) + final nce sum ----------------
__global__ void mids(const float* __restrict__ p1, const float* __restrict__ p2,
                     const float* __restrict__ g, const float* __restrict__ b,
                     float* __restrict__ sc, float* __restrict__ sh,
                     const float* __restrict__ parts, float* __restrict__ out) {
  int c = threadIdx.x;  // 128 threads
  if (c < 64) {  // wave 0: nce final sum
    float s = parts[c];
    for (int d = 1; d < 64; d <<= 1) s += __shfl_xor(s, d);
    if (c == 0) out[0] = s / 65536.0f;  // B*T*W
  }
  float s1 = 0.f, s2 = 0.f;
  for (int k = 0; k < 32; k++) {
    s1 += p1[k * 128 + c];
    s2 += p2[k * 128 + c];
  }
  float mean = s1 * (1.f / 4096.f);
  float var = s2 * (1.f / 4096.f) - mean * mean;  // biased (BN train)
  float scale = g[c] * rsqrtf(var + 1e-5f);
  sc[c] = scale;
  sh[c] = b[c] - mean * scale;
}

// ---------------- BN-apply + ReLU + GEMM2 -> proj (fp32) ----------------
__global__ __launch_bounds__(256) void proj_gemm2(const float* __restrict__ h1,
                                                  const float* __restrict__ sc,
                                                  const float* __restrict__ sh,
                                                  const float* __restrict__ pw2,
                                                  const float* __restrict__ pb2,
                                                  float* __restrict__ out) {
  __shared__ float pw2s[64][129];  // +1 pad breaks bank aliasing
  __shared__ float hs[16][129];
  __shared__ float scs[128], shs[128];
  int tid = threadIdx.x;
  for (int idx = tid; idx < 64 * 128; idx += 256) pw2s[idx >> 7][idx & 127] = pw2[idx];
  if (tid < 128) { scs[tid] = sc[tid]; shs[tid] = sh[tid]; }
  __syncthreads();
  int r0 = blockIdx.x * 64;
  float bb = pb2[tid & 63];
  for (int ch = 0; ch < 4; ch++) {
    int rr0 = r0 + ch * 16;
    for (int idx = tid; idx < 16 * 128; idx += 256) {
      int r = idx >> 7, c = idx & 127;
      float v = h1[(size_t)(rr0 + r) * 128 + c];
      hs[r][c] = fmaxf(v * scs[c] + shs[c], 0.f);
    }
    __syncthreads();
    int oc = tid & 63, og = tid >> 6;
#pragma unroll
    for (int q = 0; q < 4; q++) {
      int row = og * 4 + q;
      float s = bb;
      for (int c = 0; c < 128; c++) s += hs[row][c] * pw2s[oc][c];
      out[(size_t)(rr0 + row) * 64 + oc] = s;
    }
    __syncthreads();
  }
}

extern "C" void kernel_launch(void* const* d_in, const int* in_sizes, int n_in,
                              void* d_out, int out_size, void* d_ws, size_t ws_size,
                              hipStream_t stream) {
  const float* features = (const float*)d_in[0];
  const float* c_t      = (const float*)d_in[1];
  const float* Wk_w     = (const float*)d_in[2];
  const float* Wk_b     = (const float*)d_in[3];
  const float* pw1      = (const float*)d_in[4];
  const float* pb1      = (const float*)d_in[5];
  const float* bn_gamma = (const float*)d_in[6];
  const float* bn_beta  = (const float*)d_in[7];
  const float* pw2      = (const float*)d_in[8];
  const float* pb2      = (const float*)d_in[9];
  const int*   tsp      = (const int*)d_in[10];
  float* out = (float*)d_out;

  // workspace carve-up (~49 MB total)
  char* ws = (char*)d_ws;
  size_t off = 0;
  auto carve = [&](size_t bytes) { void* p = ws + off; off += (bytes + 255) & ~(size_t)255; return p; };
  unsigned short* ct_bf  = (unsigned short*)carve((size_t)4096 * 512 * 2);   // c_t bf16 [bw][h]
  unsigned short* wk_bf  = (unsigned short*)carve((size_t)4096 * 512 * 2);   // Wk bf16 [tc][h]
  unsigned short* pw1_bf = (unsigned short*)carve((size_t)128 * 512 * 2);
  unsigned short* F      = (unsigned short*)carve((size_t)NSLAB * 512 * 256 * 2);
  unsigned short* pred   = (unsigned short*)carve((size_t)4096 * 4096 * 2);  // [bw][tc] natural
  float* h1     = (float*)carve((size_t)4096 * 128 * 4);
  float* bnp1   = (float*)carve((size_t)32 * 128 * 4);
  float* bnp2   = (float*)carve((size_t)32 * 128 * 4);
  float* bnsc   = (float*)carve((size_t)128 * 4);
  float* bnsh   = (float*)carve((size_t)128 * 4);
  float* parts  = (float*)carve((size_t)2048 * 4);
  float* rowsum = (float*)carve((size_t)65536 * 4);
  float* diagv  = (float*)carve((size_t)65536 * 4);

  prep_all<<<4672, 256, 0, stream>>>(c_t, Wk_w, pw1, features, ct_bf, wk_bf, pw1_bf, F, tsp);
  hipMemsetAsync(rowsum, 0, (size_t)65536 * 4, stream);  // atomic accumulator init

  // pred[bw][tc] = c_t @ Wk^T + Wk_b   (M=N=4096, K=512) - natural layout
  gemm_bt<0><<<dim3(32, 32), 256, 0, stream>>>(ct_bf, wk_bf, Wk_b, pred, nullptr, 512, 4096);
  // h1 = c_t2d @ pw1^T + pb1   (M=4096, N=128, K=512)
  gemm_bt<1><<<dim3(32, 1), 256, 0, stream>>>(ct_bf, pw1_bf, pb1, nullptr, h1, 512, 128);

  scores_gemm<<<dim3(128, 4, 4), 256, 0, stream>>>(F, pred, tsp, rowsum, diagv);
  nce_rows<<<64, 256, 0, stream>>>(rowsum, diagv, parts);

  bn_stage1<<<32, 128, 0, stream>>>(h1, bnp1, bnp2);
  mids<<<1, 128, 0, stream>>>(bnp1, bnp2, bn_gamma, bn_beta, bnsc, bnsh, parts, out);
  proj_gemm2<<<64, 256, 0, stream>>>(h1, bnsc, bnsh, pw2, pb2, out + 1);
}